// Round 1
// baseline (418.374 us; speedup 1.0000x reference)
//
#include <hip/hip_runtime.h>
#include <math.h>

#define NN 10000        // nodes
#define EIN 160000      // input edges
#define ETOT 170000     // + self loops
#define NG 64           // graphs
#define INDIM 128
#define HID 64
#define HEADS 8
#define D0 512          // HEADS*HID
#define OUTD 10

// ---------------- CSR build ----------------
__global__ void count_kernel(const int* __restrict__ ei, int* __restrict__ cnt) {
    int i = blockIdx.x * 256 + threadIdx.x;
    if (i >= ETOT) return;
    int dst = (i < EIN) ? ei[EIN + i] : (i - EIN);
    atomicAdd(&cnt[dst], 1);
}

__global__ __launch_bounds__(1024) void scan_kernel(const int* __restrict__ cnt,
                                                    int* __restrict__ row_ptr,
                                                    int* __restrict__ cursor) {
    __shared__ int ssum[1024];
    int t = threadIdx.x;
    const int PER = 10;
    int base = t * PER;
    int loc[PER];
    int s = 0;
#pragma unroll
    for (int i = 0; i < PER; i++) {
        int v = (base + i < NN) ? cnt[base + i] : 0;
        loc[i] = s; s += v;
    }
    ssum[t] = s;
    __syncthreads();
    for (int off = 1; off < 1024; off <<= 1) {
        int v = (t >= off) ? ssum[t - off] : 0;
        __syncthreads();
        ssum[t] += v;
        __syncthreads();
    }
    int bs = (t > 0) ? ssum[t - 1] : 0;
#pragma unroll
    for (int i = 0; i < PER; i++) {
        if (base + i < NN) { int v = bs + loc[i]; row_ptr[base + i] = v; cursor[base + i] = v; }
    }
    if (t == 0) row_ptr[NN] = ssum[1023];
}

__global__ void scatter_kernel(const int* __restrict__ ei, int* __restrict__ cursor,
                               int* __restrict__ col_src) {
    int i = blockIdx.x * 256 + threadIdx.x;
    if (i >= ETOT) return;
    int src, dst;
    if (i < EIN) { src = ei[i]; dst = ei[EIN + i]; }
    else { src = i - EIN; dst = src; }
    int pos = atomicAdd(&cursor[dst], 1);
    col_src[pos] = src;
}

// ---------------- fp32 tiled GEMM: C[M,N] = A[M,K] @ B[K,N] ----------------
#define BM 64
#define BN 64
#define BKK 32
__global__ __launch_bounds__(256) void gemm_f32(const float* __restrict__ A,
                                                const float* __restrict__ B,
                                                float* __restrict__ C,
                                                int M, int N, int K) {
    __shared__ float As[BKK][BM + 1];
    __shared__ float Bs[BKK][BN];
    int tid = threadIdx.x;
    int tx = tid & 15, ty = tid >> 4;
    int block_row = blockIdx.y * BM;
    int block_col = blockIdx.x * BN;

    float acc[4][4] = {};

    int arow = tid >> 3;          // 0..31
    int acol4 = (tid & 7) * 4;    // 0..28
    int brow = tid >> 4;          // 0..15
    int bcol4 = (tid & 15) * 4;   // 0..60

    for (int k0 = 0; k0 < K; k0 += BKK) {
#pragma unroll
        for (int p = 0; p < 2; ++p) {
            int r = arow + p * 32;
            int gr = block_row + r;
            float4 v = make_float4(0.f, 0.f, 0.f, 0.f);
            if (gr < M) v = *(const float4*)(A + (size_t)gr * K + k0 + acol4);
            As[acol4 + 0][r] = v.x;
            As[acol4 + 1][r] = v.y;
            As[acol4 + 2][r] = v.z;
            As[acol4 + 3][r] = v.w;
        }
#pragma unroll
        for (int p = 0; p < 2; ++p) {
            int r = brow + p * 16;
            float4 v = *(const float4*)(B + (size_t)(k0 + r) * N + block_col + bcol4);
            *(float4*)&Bs[r][bcol4] = v;
        }
        __syncthreads();
#pragma unroll
        for (int k = 0; k < BKK; ++k) {
            float ra[4], rb[4];
#pragma unroll
            for (int i = 0; i < 4; i++) ra[i] = As[k][ty * 4 + i];
#pragma unroll
            for (int j = 0; j < 4; j++) rb[j] = Bs[k][tx * 4 + j];
#pragma unroll
            for (int i = 0; i < 4; i++)
#pragma unroll
                for (int j = 0; j < 4; j++)
                    acc[i][j] += ra[i] * rb[j];
        }
        __syncthreads();
    }
#pragma unroll
    for (int i = 0; i < 4; i++) {
        int gr = block_row + ty * 4 + i;
        if (gr >= M) continue;
#pragma unroll
        for (int j = 0; j < 4; j++) {
            C[(size_t)gr * N + block_col + tx * 4 + j] = acc[i][j];
        }
    }
}

// ---------------- per-(node,head) attention dots ----------------
__global__ void node_attn_kernel(const float* __restrict__ h, const float* __restrict__ asrc,
                                 const float* __restrict__ adst, float* __restrict__ a_s,
                                 float* __restrict__ a_d, int H, int total) {
    int id = blockIdx.x * 4 + (threadIdx.x >> 6);
    int lane = threadIdx.x & 63;
    if (id >= total) return;
    int node = id / H, head = id - node * H;
    float v = h[(size_t)node * H * 64 + head * 64 + lane];
    float ds = v * asrc[head * 64 + lane];
    float dd = v * adst[head * 64 + lane];
    for (int o = 32; o; o >>= 1) { ds += __shfl_xor(ds, o); dd += __shfl_xor(dd, o); }
    if (lane == 0) { a_s[id] = ds; a_d[id] = dd; }
}

// ---------------- GAT aggregate, 8 heads x 64 ch ----------------
__global__ __launch_bounds__(256) void gat_agg8(const float* __restrict__ h,      // [N,512]
                                                const float* __restrict__ a_s,    // [N,8]
                                                const float* __restrict__ a_d,    // [N,8]
                                                const int* __restrict__ row_ptr,
                                                const int* __restrict__ col_src,
                                                const float* __restrict__ bias,   // [512]
                                                float* __restrict__ out,          // [N,512]
                                                int do_relu) {
    int n = blockIdx.x;
    int tid = threadIdx.x;
    int c0 = tid, c1 = tid + 256;
    int h0 = tid >> 6, h1 = h0 + 4;
    __shared__ float ad_sh[8];
    __shared__ float m_sh[8];
    __shared__ float red[4][8];
    if (tid < 8) ad_sh[tid] = a_d[n * 8 + tid];
    __syncthreads();
    int r0 = row_ptr[n], r1 = row_ptr[n + 1];

    // pass 1: max per head
    float lm[8];
#pragma unroll
    for (int i = 0; i < 8; i++) lm[i] = -1e30f;
    for (int k = r0 + tid; k < r1; k += 256) {
        int s = col_src[k];
#pragma unroll
        for (int hh = 0; hh < 8; ++hh) {
            float e = a_s[s * 8 + hh] + ad_sh[hh];
            e = e > 0.f ? e : 0.2f * e;
            lm[hh] = fmaxf(lm[hh], e);
        }
    }
    int lane = tid & 63, wid = tid >> 6;
#pragma unroll
    for (int hh = 0; hh < 8; ++hh)
        for (int o = 32; o; o >>= 1) lm[hh] = fmaxf(lm[hh], __shfl_xor(lm[hh], o));
    if (lane == 0) {
#pragma unroll
        for (int hh = 0; hh < 8; hh++) red[wid][hh] = lm[hh];
    }
    __syncthreads();
    if (tid < 8) {
        m_sh[tid] = fmaxf(fmaxf(red[0][tid], red[1][tid]), fmaxf(red[2][tid], red[3][tid]));
    }
    __syncthreads();

    float m0 = m_sh[h0], m1 = m_sh[h1];
    float ad0 = ad_sh[h0], ad1 = ad_sh[h1];
    float acc0 = 0.f, acc1 = 0.f, s0 = 0.f, s1 = 0.f;
    for (int k = r0; k < r1; ++k) {
        int s = col_src[k];
        float e0 = a_s[s * 8 + h0] + ad0; e0 = e0 > 0.f ? e0 : 0.2f * e0;
        float e1 = a_s[s * 8 + h1] + ad1; e1 = e1 > 0.f ? e1 : 0.2f * e1;
        float al0 = __expf(e0 - m0), al1 = __expf(e1 - m1);
        acc0 += al0 * h[(size_t)s * 512 + c0];
        acc1 += al1 * h[(size_t)s * 512 + c1];
        s0 += al0; s1 += al1;
    }
    float o0 = acc0 / (s0 + 1e-16f) + bias[c0];
    float o1 = acc1 / (s1 + 1e-16f) + bias[c1];
    if (do_relu) { o0 = fmaxf(o0, 0.f); o1 = fmaxf(o1, 0.f); }
    out[(size_t)n * 512 + c0] = o0;
    out[(size_t)n * 512 + c1] = o1;
}

// ---------------- GAT aggregate, 1 head x 64 ch (layer 2) ----------------
__global__ __launch_bounds__(256) void gat_agg1(const float* __restrict__ h,    // [N,64]
                                                const float* __restrict__ a_s,  // [N]
                                                const float* __restrict__ a_d,  // [N]
                                                const int* __restrict__ row_ptr,
                                                const int* __restrict__ col_src,
                                                const float* __restrict__ bias, // [64]
                                                float* __restrict__ out) {
    int n = blockIdx.x * 4 + (threadIdx.x >> 6);
    int lane = threadIdx.x & 63;
    if (n >= NN) return;
    int r0 = row_ptr[n], r1 = row_ptr[n + 1];
    float ad = a_d[n];
    float lm = -1e30f;
    for (int k = r0 + lane; k < r1; k += 64) {
        float e = a_s[col_src[k]] + ad;
        e = e > 0.f ? e : 0.2f * e;
        lm = fmaxf(lm, e);
    }
    for (int o = 32; o; o >>= 1) lm = fmaxf(lm, __shfl_xor(lm, o));
    float acc = 0.f, ssum = 0.f;
    for (int k = r0; k < r1; ++k) {
        int s = col_src[k];
        float e = a_s[s] + ad; e = e > 0.f ? e : 0.2f * e;
        float al = __expf(e - lm);
        acc += al * h[(size_t)s * 64 + lane];
        ssum += al;
    }
    out[(size_t)n * 64 + lane] = acc / (ssum + 1e-16f) + bias[lane];
}

// ---------------- pooling ----------------
__device__ inline unsigned fenc(float f) {
    unsigned u = __float_as_uint(f);
    return (u & 0x80000000u) ? ~u : (u | 0x80000000u);
}
__device__ inline float fdec(unsigned u) {
    return (u & 0x80000000u) ? __uint_as_float(u ^ 0x80000000u) : __uint_as_float(~u);
}

__global__ void pool_init(float* sums, unsigned* maxs, int* cnt) {
    int i = blockIdx.x * 256 + threadIdx.x;
    if (i < NG * 64) { sums[i] = 0.f; maxs[i] = 0u; }
    if (i < NG) cnt[i] = 0;
}

__global__ void pool_accum(const float* __restrict__ h, const int* __restrict__ batch,
                           float* __restrict__ sums, unsigned* __restrict__ maxs,
                           int* __restrict__ cnt) {
    int n = blockIdx.x * 4 + (threadIdx.x >> 6);
    int lane = threadIdx.x & 63;
    if (n >= NN) return;
    int g = batch[n];
    float v = h[(size_t)n * 64 + lane];
    atomicAdd(&sums[g * 64 + lane], v);
    atomicMax(&maxs[g * 64 + lane], fenc(v));
    if (lane == 0) atomicAdd(&cnt[g], 1);
}

__global__ void classifier_kernel(const float* __restrict__ sums, const unsigned* __restrict__ maxs,
                                  const int* __restrict__ cnt,
                                  const float* __restrict__ cW1, const float* __restrict__ cb1,
                                  const float* __restrict__ cW2, const float* __restrict__ cb2,
                                  float* __restrict__ out) {
    int g = blockIdx.x;
    int t = threadIdx.x; // 64
    __shared__ float gv[128];
    __shared__ float c1[64];
    float c = (float)(cnt[g] > 1 ? cnt[g] : 1);
    gv[t] = sums[g * 64 + t] / c;
    gv[64 + t] = fdec(maxs[g * 64 + t]);
    __syncthreads();
    float acc = cb1[t];
    for (int k = 0; k < 128; k++) acc += gv[k] * cW1[k * 64 + t];
    c1[t] = fmaxf(acc, 0.f);
    __syncthreads();
    if (t < OUTD) {
        float o = cb2[t];
        for (int k = 0; k < 64; k++) o += c1[k] * cW2[k * OUTD + t];
        out[g * OUTD + t] = o;
    }
}

// ---------------- launch ----------------
extern "C" void kernel_launch(void* const* d_in, const int* in_sizes, int n_in,
                              void* d_out, int out_size, void* d_ws, size_t ws_size,
                              hipStream_t stream) {
    const float* x     = (const float*)d_in[0];
    const int*   ei    = (const int*)d_in[1];
    const int*   batch = (const int*)d_in[2];
    const float* W0    = (const float*)d_in[3];
    const float* asrc0 = (const float*)d_in[4];
    const float* adst0 = (const float*)d_in[5];
    const float* b0    = (const float*)d_in[6];
    const float* W1    = (const float*)d_in[7];
    const float* asrc1 = (const float*)d_in[8];
    const float* adst1 = (const float*)d_in[9];
    const float* b1    = (const float*)d_in[10];
    const float* W2    = (const float*)d_in[11];
    const float* asrc2 = (const float*)d_in[12];
    const float* adst2 = (const float*)d_in[13];
    const float* b2    = (const float*)d_in[14];
    const float* cW1   = (const float*)d_in[15];
    const float* cb1   = (const float*)d_in[16];
    const float* cW2   = (const float*)d_in[17];
    const float* cb2   = (const float*)d_in[18];
    float* out = (float*)d_out;

    // workspace carve-up (bytes)
    char* ws = (char*)d_ws;
    size_t off = 0;
    auto alloc = [&](size_t bytes) { void* p = ws + off; off += (bytes + 255) & ~(size_t)255; return p; };
    float* bufA    = (float*)alloc((size_t)NN * D0 * 4);   // 20.48 MB
    float* bufB    = (float*)alloc((size_t)NN * D0 * 4);   // 20.48 MB
    float* bufC    = (float*)alloc((size_t)NN * 64 * 4);   // 2.56 MB
    float* bufD    = (float*)alloc((size_t)NN * 64 * 4);   // 2.56 MB
    float* a_s     = (float*)alloc((size_t)NN * HEADS * 4);
    float* a_d     = (float*)alloc((size_t)NN * HEADS * 4);
    int*   cnt     = (int*)alloc((size_t)NN * 4);
    int*   row_ptr = (int*)alloc((size_t)(NN + 1) * 4);
    int*   cursor  = (int*)alloc((size_t)NN * 4);
    int*   col_src = (int*)alloc((size_t)ETOT * 4);
    float* psums   = (float*)alloc((size_t)NG * 64 * 4);
    unsigned* pmax = (unsigned*)alloc((size_t)NG * 64 * 4);
    int*   pcnt    = (int*)alloc((size_t)NG * 4);
    (void)ws_size; (void)n_in; (void)in_sizes; (void)out_size;

    // ---- CSR build ----
    hipMemsetAsync(cnt, 0, (size_t)NN * 4, stream);
    count_kernel<<<(ETOT + 255) / 256, 256, 0, stream>>>(ei, cnt);
    scan_kernel<<<1, 1024, 0, stream>>>(cnt, row_ptr, cursor);
    scatter_kernel<<<(ETOT + 255) / 256, 256, 0, stream>>>(ei, cursor, col_src);

    dim3 gemm_grid8(D0 / BN, (NN + BM - 1) / BM);
    dim3 gemm_grid1(64 / BN, (NN + BM - 1) / BM);

    // ---- layer 0 ----
    gemm_f32<<<gemm_grid8, 256, 0, stream>>>(x, W0, bufA, NN, D0, INDIM);
    node_attn_kernel<<<(NN * HEADS + 3) / 4, 256, 0, stream>>>(bufA, asrc0, adst0, a_s, a_d, HEADS, NN * HEADS);
    gat_agg8<<<NN, 256, 0, stream>>>(bufA, a_s, a_d, row_ptr, col_src, b0, bufB, 1);

    // ---- layer 1 ----
    gemm_f32<<<gemm_grid8, 256, 0, stream>>>(bufB, W1, bufA, NN, D0, D0);
    node_attn_kernel<<<(NN * HEADS + 3) / 4, 256, 0, stream>>>(bufA, asrc1, adst1, a_s, a_d, HEADS, NN * HEADS);
    gat_agg8<<<NN, 256, 0, stream>>>(bufA, a_s, a_d, row_ptr, col_src, b1, bufB, 1);

    // ---- layer 2 (1 head) ----
    gemm_f32<<<gemm_grid1, 256, 0, stream>>>(bufB, W2, bufC, NN, 64, D0);
    node_attn_kernel<<<(NN + 3) / 4, 256, 0, stream>>>(bufC, asrc2, adst2, a_s, a_d, 1, NN);
    gat_agg1<<<(NN + 3) / 4, 256, 0, stream>>>(bufC, a_s, a_d, row_ptr, col_src, b2, bufD);

    // ---- pooling + classifier ----
    pool_init<<<(NG * 64 + 255) / 256, 256, 0, stream>>>(psums, pmax, pcnt);
    pool_accum<<<(NN + 3) / 4, 256, 0, stream>>>(bufD, batch, psums, pmax, pcnt);
    classifier_kernel<<<NG, 64, 0, stream>>>(psums, pmax, pcnt, cW1, cb1, cW2, cb2, out);
}

// Round 2
// 353.629 us; speedup vs baseline: 1.1831x; 1.1831x over previous
//
#include <hip/hip_runtime.h>
#include <hip/hip_bf16.h>
#include <math.h>

#define NN 10000        // nodes
#define EIN 160000      // input edges
#define ETOT 170000     // + self loops
#define NG 64           // graphs
#define INDIM 128
#define HID 64
#define HEADS 8
#define D0 512          // HEADS*HID
#define OUTD 10

using bfrag = __attribute__((ext_vector_type(8))) short;   // 8 bf16
using ffrag = __attribute__((ext_vector_type(4))) float;   // 4 f32

// ---------------- casts ----------------
__global__ void cast_bf16_kernel(const float* __restrict__ src, __hip_bfloat16* __restrict__ dst, int n) {
    int i = blockIdx.x * 256 + threadIdx.x;
    if (i < n) dst[i] = __float2bfloat16(src[i]);
}

// src [R][C] fp32 -> dst [C][R] bf16
__global__ __launch_bounds__(256) void transpose_cast_kernel(const float* __restrict__ src,
                                                             __hip_bfloat16* __restrict__ dst,
                                                             int R, int C) {
    __shared__ float tile[32][33];
    int cb = blockIdx.x * 32, rb = blockIdx.y * 32;
    int tx = threadIdx.x & 31, ty = threadIdx.x >> 5; // 32 x 8
#pragma unroll
    for (int i = 0; i < 32; i += 8) {
        int r = rb + ty + i, c = cb + tx;
        tile[ty + i][tx] = (r < R && c < C) ? src[(size_t)r * C + c] : 0.f;
    }
    __syncthreads();
#pragma unroll
    for (int i = 0; i < 32; i += 8) {
        int c = cb + ty + i, r = rb + tx;
        if (c < C && r < R) dst[(size_t)c * R + r] = __float2bfloat16(tile[tx][ty + i]);
    }
}

// ---------------- CSR build ----------------
__global__ void count_kernel(const int* __restrict__ ei, int* __restrict__ cnt) {
    int i = blockIdx.x * 256 + threadIdx.x;
    if (i >= ETOT) return;
    int dst = (i < EIN) ? ei[EIN + i] : (i - EIN);
    atomicAdd(&cnt[dst], 1);
}

__global__ __launch_bounds__(1024) void scan_kernel(const int* __restrict__ cnt,
                                                    int* __restrict__ row_ptr,
                                                    int* __restrict__ cursor) {
    __shared__ int ssum[1024];
    int t = threadIdx.x;
    const int PER = 10;
    int base = t * PER;
    int loc[PER];
    int s = 0;
#pragma unroll
    for (int i = 0; i < PER; i++) {
        int v = (base + i < NN) ? cnt[base + i] : 0;
        loc[i] = s; s += v;
    }
    ssum[t] = s;
    __syncthreads();
    for (int off = 1; off < 1024; off <<= 1) {
        int v = (t >= off) ? ssum[t - off] : 0;
        __syncthreads();
        ssum[t] += v;
        __syncthreads();
    }
    int bs = (t > 0) ? ssum[t - 1] : 0;
#pragma unroll
    for (int i = 0; i < PER; i++) {
        if (base + i < NN) { int v = bs + loc[i]; row_ptr[base + i] = v; cursor[base + i] = v; }
    }
    if (t == 0) row_ptr[NN] = ssum[1023];
}

__global__ void scatter_kernel(const int* __restrict__ ei, int* __restrict__ cursor,
                               int* __restrict__ col_src) {
    int i = blockIdx.x * 256 + threadIdx.x;
    if (i >= ETOT) return;
    int src, dst;
    if (i < EIN) { src = ei[i]; dst = ei[EIN + i]; }
    else { src = i - EIN; dst = src; }
    int pos = atomicAdd(&cursor[dst], 1);
    col_src[pos] = src;
}

// ---------------- bf16 MFMA GEMM: C[M,N] = A[M,K] @ BT[N,K]^T ----------------
#define GBM 128
#define GBN 128
#define GBK 32
#define LPAD 8   // pad to 40 shorts = 80B rows (16B aligned, bank stride 20 -> 2-way free)

__global__ __launch_bounds__(256) void gemm_bt_bf16(const __hip_bfloat16* __restrict__ A,
                                                    const __hip_bfloat16* __restrict__ BT,
                                                    float* __restrict__ C,
                                                    int M, int N, int K) {
    __shared__ __align__(16) short As[GBM][GBK + LPAD];
    __shared__ __align__(16) short Bs[GBN][GBK + LPAD];
    int tid = threadIdx.x;
    int wid = tid >> 6, lane = tid & 63;
    int wr = wid >> 1, wc = wid & 1;
    int brow = blockIdx.y * GBM, bcol = blockIdx.x * GBN;

    ffrag acc[4][4] = {};

    int srow = tid >> 2;        // 0..63
    int skq  = (tid & 3) * 8;   // 0,8,16,24

    int kq = (lane >> 4) * 8;
    int ra = lane & 15;

    for (int k0 = 0; k0 < K; k0 += GBK) {
#pragma unroll
        for (int p = 0; p < 2; ++p) {
            int r = srow + p * 64;
            int gr = brow + r;
            bfrag va = {0,0,0,0,0,0,0,0};
            if (gr < M) va = *(const bfrag*)(A + (size_t)gr * K + k0 + skq);
            *(bfrag*)&As[r][skq] = va;
            int gc = bcol + r;
            bfrag vb = {0,0,0,0,0,0,0,0};
            if (gc < N) vb = *(const bfrag*)(BT + (size_t)gc * K + k0 + skq);
            *(bfrag*)&Bs[r][skq] = vb;
        }
        __syncthreads();
        bfrag af[4], bf[4];
#pragma unroll
        for (int m = 0; m < 4; ++m) af[m] = *(const bfrag*)&As[wr * 64 + m * 16 + ra][kq];
#pragma unroll
        for (int n = 0; n < 4; ++n) bf[n] = *(const bfrag*)&Bs[wc * 64 + n * 16 + ra][kq];
#pragma unroll
        for (int m = 0; m < 4; ++m)
#pragma unroll
            for (int n = 0; n < 4; ++n)
                acc[m][n] = __builtin_amdgcn_mfma_f32_16x16x32_bf16(af[m], bf[n], acc[m][n], 0, 0, 0);
        __syncthreads();
    }

    int cr = (lane >> 4) * 4;
    int cc = lane & 15;
#pragma unroll
    for (int m = 0; m < 4; ++m) {
#pragma unroll
        for (int n = 0; n < 4; ++n) {
#pragma unroll
            for (int r = 0; r < 4; ++r) {
                int grow = brow + wr * 64 + m * 16 + cr + r;
                int gcol = bcol + wc * 64 + n * 16 + cc;
                if (grow < M && gcol < N)
                    C[(size_t)grow * N + gcol] = acc[m][n][r];
            }
        }
    }
}

// ---------------- per-(node,head) attention dots ----------------
__global__ void node_attn_kernel(const float* __restrict__ h, const float* __restrict__ asrc,
                                 const float* __restrict__ adst, float* __restrict__ a_s,
                                 float* __restrict__ a_d, int H, int total) {
    int id = blockIdx.x * 4 + (threadIdx.x >> 6);
    int lane = threadIdx.x & 63;
    if (id >= total) return;
    int node = id / H, head = id - node * H;
    float v = h[(size_t)node * H * 64 + head * 64 + lane];
    float ds = v * asrc[head * 64 + lane];
    float dd = v * adst[head * 64 + lane];
    for (int o = 32; o; o >>= 1) { ds += __shfl_xor(ds, o); dd += __shfl_xor(dd, o); }
    if (lane == 0) { a_s[id] = ds; a_d[id] = dd; }
}

// ---------------- GAT aggregate, 8 heads x 64 ch -> bf16 out (relu) ----------------
__global__ __launch_bounds__(256) void gat_agg8(const float* __restrict__ h,      // [N,512] f32
                                                const float* __restrict__ a_s,    // [N,8]
                                                const float* __restrict__ a_d,    // [N,8]
                                                const int* __restrict__ row_ptr,
                                                const int* __restrict__ col_src,
                                                const float* __restrict__ bias,   // [512]
                                                __hip_bfloat16* __restrict__ out) // [N,512] bf16
{
    int n = blockIdx.x;
    int tid = threadIdx.x;
    int c0 = tid, c1 = tid + 256;
    int h0 = tid >> 6, h1 = h0 + 4;
    __shared__ float ad_sh[8];
    __shared__ float m_sh[8];
    __shared__ float red[4][8];
    if (tid < 8) ad_sh[tid] = a_d[n * 8 + tid];
    __syncthreads();
    int r0 = row_ptr[n], r1 = row_ptr[n + 1];

    // pass 1: max per head
    float lm[8];
#pragma unroll
    for (int i = 0; i < 8; i++) lm[i] = -1e30f;
    for (int k = r0 + tid; k < r1; k += 256) {
        int s = col_src[k];
#pragma unroll
        for (int hh = 0; hh < 8; ++hh) {
            float e = a_s[s * 8 + hh] + ad_sh[hh];
            e = e > 0.f ? e : 0.2f * e;
            lm[hh] = fmaxf(lm[hh], e);
        }
    }
    int lane = tid & 63, wid = tid >> 6;
#pragma unroll
    for (int hh = 0; hh < 8; ++hh)
        for (int o = 32; o; o >>= 1) lm[hh] = fmaxf(lm[hh], __shfl_xor(lm[hh], o));
    if (lane == 0) {
#pragma unroll
        for (int hh = 0; hh < 8; hh++) red[wid][hh] = lm[hh];
    }
    __syncthreads();
    if (tid < 8) {
        m_sh[tid] = fmaxf(fmaxf(red[0][tid], red[1][tid]), fmaxf(red[2][tid], red[3][tid]));
    }
    __syncthreads();

    float m0 = m_sh[h0], m1 = m_sh[h1];
    float ad0 = ad_sh[h0], ad1 = ad_sh[h1];
    float acc0 = 0.f, acc1 = 0.f, s0 = 0.f, s1 = 0.f;
    for (int k = r0; k < r1; ++k) {
        int s = col_src[k];
        float e0 = a_s[s * 8 + h0] + ad0; e0 = e0 > 0.f ? e0 : 0.2f * e0;
        float e1 = a_s[s * 8 + h1] + ad1; e1 = e1 > 0.f ? e1 : 0.2f * e1;
        float al0 = __expf(e0 - m0), al1 = __expf(e1 - m1);
        acc0 += al0 * h[(size_t)s * 512 + c0];
        acc1 += al1 * h[(size_t)s * 512 + c1];
        s0 += al0; s1 += al1;
    }
    float o0 = acc0 / (s0 + 1e-16f) + bias[c0];
    float o1 = acc1 / (s1 + 1e-16f) + bias[c1];
    o0 = fmaxf(o0, 0.f); o1 = fmaxf(o1, 0.f);
    out[(size_t)n * 512 + c0] = __float2bfloat16(o0);
    out[(size_t)n * 512 + c1] = __float2bfloat16(o1);
}

// ---------------- GAT aggregate, 1 head x 64 ch (layer 2) ----------------
__global__ __launch_bounds__(256) void gat_agg1(const float* __restrict__ h,    // [N,64]
                                                const float* __restrict__ a_s,  // [N]
                                                const float* __restrict__ a_d,  // [N]
                                                const int* __restrict__ row_ptr,
                                                const int* __restrict__ col_src,
                                                const float* __restrict__ bias, // [64]
                                                float* __restrict__ out) {
    int n = blockIdx.x * 4 + (threadIdx.x >> 6);
    int lane = threadIdx.x & 63;
    if (n >= NN) return;
    int r0 = row_ptr[n], r1 = row_ptr[n + 1];
    float ad = a_d[n];
    float lm = -1e30f;
    for (int k = r0 + lane; k < r1; k += 64) {
        float e = a_s[col_src[k]] + ad;
        e = e > 0.f ? e : 0.2f * e;
        lm = fmaxf(lm, e);
    }
    for (int o = 32; o; o >>= 1) lm = fmaxf(lm, __shfl_xor(lm, o));
    float acc = 0.f, ssum = 0.f;
    for (int k = r0; k < r1; ++k) {
        int s = col_src[k];
        float e = a_s[s] + ad; e = e > 0.f ? e : 0.2f * e;
        float al = __expf(e - lm);
        acc += al * h[(size_t)s * 64 + lane];
        ssum += al;
    }
    out[(size_t)n * 64 + lane] = acc / (ssum + 1e-16f) + bias[lane];
}

// ---------------- pooling ----------------
__device__ inline unsigned fenc(float f) {
    unsigned u = __float_as_uint(f);
    return (u & 0x80000000u) ? ~u : (u | 0x80000000u);
}
__device__ inline float fdec(unsigned u) {
    return (u & 0x80000000u) ? __uint_as_float(u ^ 0x80000000u) : __uint_as_float(~u);
}

__global__ void pool_init(float* sums, unsigned* maxs, int* cnt) {
    int i = blockIdx.x * 256 + threadIdx.x;
    if (i < NG * 64) { sums[i] = 0.f; maxs[i] = 0u; }
    if (i < NG) cnt[i] = 0;
}

__global__ void pool_accum(const float* __restrict__ h, const int* __restrict__ batch,
                           float* __restrict__ sums, unsigned* __restrict__ maxs,
                           int* __restrict__ cnt) {
    int n = blockIdx.x * 4 + (threadIdx.x >> 6);
    int lane = threadIdx.x & 63;
    if (n >= NN) return;
    int g = batch[n];
    float v = h[(size_t)n * 64 + lane];
    atomicAdd(&sums[g * 64 + lane], v);
    atomicMax(&maxs[g * 64 + lane], fenc(v));
    if (lane == 0) atomicAdd(&cnt[g], 1);
}

__global__ void classifier_kernel(const float* __restrict__ sums, const unsigned* __restrict__ maxs,
                                  const int* __restrict__ cnt,
                                  const float* __restrict__ cW1, const float* __restrict__ cb1,
                                  const float* __restrict__ cW2, const float* __restrict__ cb2,
                                  float* __restrict__ out) {
    int g = blockIdx.x;
    int t = threadIdx.x; // 64
    __shared__ float gv[128];
    __shared__ float c1[64];
    float c = (float)(cnt[g] > 1 ? cnt[g] : 1);
    gv[t] = sums[g * 64 + t] / c;
    gv[64 + t] = fdec(maxs[g * 64 + t]);
    __syncthreads();
    float acc = cb1[t];
    for (int k = 0; k < 128; k++) acc += gv[k] * cW1[k * 64 + t];
    c1[t] = fmaxf(acc, 0.f);
    __syncthreads();
    if (t < OUTD) {
        float o = cb2[t];
        for (int k = 0; k < 64; k++) o += c1[k] * cW2[k * OUTD + t];
        out[g * OUTD + t] = o;
    }
}

// ---------------- launch ----------------
extern "C" void kernel_launch(void* const* d_in, const int* in_sizes, int n_in,
                              void* d_out, int out_size, void* d_ws, size_t ws_size,
                              hipStream_t stream) {
    const float* x     = (const float*)d_in[0];
    const int*   ei    = (const int*)d_in[1];
    const int*   batch = (const int*)d_in[2];
    const float* W0    = (const float*)d_in[3];
    const float* asrc0 = (const float*)d_in[4];
    const float* adst0 = (const float*)d_in[5];
    const float* b0    = (const float*)d_in[6];
    const float* W1    = (const float*)d_in[7];
    const float* asrc1 = (const float*)d_in[8];
    const float* adst1 = (const float*)d_in[9];
    const float* b1    = (const float*)d_in[10];
    const float* W2    = (const float*)d_in[11];
    const float* asrc2 = (const float*)d_in[12];
    const float* adst2 = (const float*)d_in[13];
    const float* b2    = (const float*)d_in[14];
    const float* cW1   = (const float*)d_in[15];
    const float* cb1   = (const float*)d_in[16];
    const float* cW2   = (const float*)d_in[17];
    const float* cb2   = (const float*)d_in[18];
    float* out = (float*)d_out;

    char* ws = (char*)d_ws;
    size_t off = 0;
    auto alloc = [&](size_t bytes) { void* p = ws + off; off += (bytes + 255) & ~(size_t)255; return p; };
    float* bufA  = (float*)alloc((size_t)NN * D0 * 4);            // f32 GEMM out [N,512]
    __hip_bfloat16* bufBb = (__hip_bfloat16*)alloc((size_t)NN * D0 * 2); // bf16 agg out
    float* bufC  = (float*)alloc((size_t)NN * 64 * 4);
    float* bufD  = (float*)alloc((size_t)NN * 64 * 4);
    __hip_bfloat16* xb   = (__hip_bfloat16*)alloc((size_t)NN * INDIM * 2);
    __hip_bfloat16* W0T  = (__hip_bfloat16*)alloc((size_t)D0 * INDIM * 2);  // [512][128]
    __hip_bfloat16* W1T  = (__hip_bfloat16*)alloc((size_t)D0 * D0 * 2);     // [512][512]
    __hip_bfloat16* W2T  = (__hip_bfloat16*)alloc((size_t)64 * D0 * 2);     // [64][512]
    float* a_s     = (float*)alloc((size_t)NN * HEADS * 4);
    float* a_d     = (float*)alloc((size_t)NN * HEADS * 4);
    int*   cnt     = (int*)alloc((size_t)NN * 4);
    int*   row_ptr = (int*)alloc((size_t)(NN + 1) * 4);
    int*   cursor  = (int*)alloc((size_t)NN * 4);
    int*   col_src = (int*)alloc((size_t)ETOT * 4);
    float* psums   = (float*)alloc((size_t)NG * 64 * 4);
    unsigned* pmax = (unsigned*)alloc((size_t)NG * 64 * 4);
    int*   pcnt    = (int*)alloc((size_t)NG * 4);
    (void)ws_size; (void)n_in; (void)in_sizes; (void)out_size;

    // ---- weight/input casts ----
    cast_bf16_kernel<<<(NN * INDIM + 255) / 256, 256, 0, stream>>>(x, xb, NN * INDIM);
    transpose_cast_kernel<<<dim3(D0 / 32, INDIM / 32), 256, 0, stream>>>(W0, W0T, INDIM, D0);
    transpose_cast_kernel<<<dim3(D0 / 32, D0 / 32), 256, 0, stream>>>(W1, W1T, D0, D0);
    transpose_cast_kernel<<<dim3(64 / 32, D0 / 32), 256, 0, stream>>>(W2, W2T, D0, 64);

    // ---- CSR build ----
    hipMemsetAsync(cnt, 0, (size_t)NN * 4, stream);
    count_kernel<<<(ETOT + 255) / 256, 256, 0, stream>>>(ei, cnt);
    scan_kernel<<<1, 1024, 0, stream>>>(cnt, row_ptr, cursor);
    scatter_kernel<<<(ETOT + 255) / 256, 256, 0, stream>>>(ei, cursor, col_src);

    dim3 gg8(D0 / GBN, (NN + GBM - 1) / GBM);   // (4, 79)
    dim3 gg1(1, (NN + GBM - 1) / GBM);          // (1, 79)

    // ---- layer 0 ----
    gemm_bt_bf16<<<gg8, 256, 0, stream>>>(xb, W0T, bufA, NN, D0, INDIM);
    node_attn_kernel<<<(NN * HEADS + 3) / 4, 256, 0, stream>>>(bufA, asrc0, adst0, a_s, a_d, HEADS, NN * HEADS);
    gat_agg8<<<NN, 256, 0, stream>>>(bufA, a_s, a_d, row_ptr, col_src, b0, bufBb);

    // ---- layer 1 ----
    gemm_bt_bf16<<<gg8, 256, 0, stream>>>(bufBb, W1T, bufA, NN, D0, D0);
    node_attn_kernel<<<(NN * HEADS + 3) / 4, 256, 0, stream>>>(bufA, asrc1, adst1, a_s, a_d, HEADS, NN * HEADS);
    gat_agg8<<<NN, 256, 0, stream>>>(bufA, a_s, a_d, row_ptr, col_src, b1, bufBb);

    // ---- layer 2 (1 head) ----
    gemm_bt_bf16<<<gg1, 256, 0, stream>>>(bufBb, W2T, bufC, NN, 64, D0);
    node_attn_kernel<<<(NN + 3) / 4, 256, 0, stream>>>(bufC, asrc2, adst2, a_s, a_d, 1, NN);
    gat_agg1<<<(NN + 3) / 4, 256, 0, stream>>>(bufC, a_s, a_d, row_ptr, col_src, b2, bufD);

    // ---- pooling + classifier ----
    pool_init<<<(NG * 64 + 255) / 256, 256, 0, stream>>>(psums, pmax, pcnt);
    pool_accum<<<(NN + 3) / 4, 256, 0, stream>>>(bufD, batch, psums, pmax, pcnt);
    classifier_kernel<<<NG, 64, 0, stream>>>(psums, pmax, pcnt, cW1, cb1, cW2, cb2, out);
}

// Round 3
// 279.600 us; speedup vs baseline: 1.4963x; 1.2648x over previous
//
#include <hip/hip_runtime.h>
#include <hip/hip_bf16.h>
#include <math.h>

#define NN 10000        // nodes
#define EIN 160000      // input edges
#define ETOT 170000     // + self loops
#define NG 64           // graphs
#define INDIM 128
#define HID 64
#define HEADS 8
#define D0 512          // HEADS*HID
#define OUTD 10

using bfrag = __attribute__((ext_vector_type(8))) short;   // 8 bf16
using ffrag = __attribute__((ext_vector_type(4))) float;   // 4 f32

__device__ inline float bf2f(unsigned short u) { return __uint_as_float(((unsigned)u) << 16); }
__device__ inline unsigned short f2bf(float f) {
    __hip_bfloat16 b = __float2bfloat16(f);
    return *reinterpret_cast<unsigned short*>(&b);
}

// ---------------- casts ----------------
__global__ void cast_bf16_kernel(const float* __restrict__ src, __hip_bfloat16* __restrict__ dst, int n) {
    int i = blockIdx.x * 256 + threadIdx.x;
    if (i < n) dst[i] = __float2bfloat16(src[i]);
}

// src [R][C] fp32 -> dst [C][R] bf16
__global__ __launch_bounds__(256) void transpose_cast_kernel(const float* __restrict__ src,
                                                             __hip_bfloat16* __restrict__ dst,
                                                             int R, int C) {
    __shared__ float tile[32][33];
    int cb = blockIdx.x * 32, rb = blockIdx.y * 32;
    int tx = threadIdx.x & 31, ty = threadIdx.x >> 5; // 32 x 8
#pragma unroll
    for (int i = 0; i < 32; i += 8) {
        int r = rb + ty + i, c = cb + tx;
        tile[ty + i][tx] = (r < R && c < C) ? src[(size_t)r * C + c] : 0.f;
    }
    __syncthreads();
#pragma unroll
    for (int i = 0; i < 32; i += 8) {
        int c = cb + ty + i, r = rb + tx;
        if (c < C && r < R) dst[(size_t)c * R + r] = __float2bfloat16(tile[tx][ty + i]);
    }
}

// ---------------- CSR build ----------------
__global__ void count_kernel(const int* __restrict__ ei, int* __restrict__ cnt) {
    int i = blockIdx.x * 256 + threadIdx.x;
    if (i >= ETOT) return;
    int dst = (i < EIN) ? ei[EIN + i] : (i - EIN);
    atomicAdd(&cnt[dst], 1);
}

__global__ __launch_bounds__(1024) void scan_kernel(const int* __restrict__ cnt,
                                                    int* __restrict__ row_ptr,
                                                    int* __restrict__ cursor) {
    __shared__ int ssum[1024];
    int t = threadIdx.x;
    const int PER = 10;
    int base = t * PER;
    int loc[PER];
    int s = 0;
#pragma unroll
    for (int i = 0; i < PER; i++) {
        int v = (base + i < NN) ? cnt[base + i] : 0;
        loc[i] = s; s += v;
    }
    ssum[t] = s;
    __syncthreads();
    for (int off = 1; off < 1024; off <<= 1) {
        int v = (t >= off) ? ssum[t - off] : 0;
        __syncthreads();
        ssum[t] += v;
        __syncthreads();
    }
    int bs = (t > 0) ? ssum[t - 1] : 0;
#pragma unroll
    for (int i = 0; i < PER; i++) {
        if (base + i < NN) { int v = bs + loc[i]; row_ptr[base + i] = v; cursor[base + i] = v; }
    }
    if (t == 0) row_ptr[NN] = ssum[1023];
}

__global__ void scatter_kernel(const int* __restrict__ ei, int* __restrict__ cursor,
                               int* __restrict__ col_src) {
    int i = blockIdx.x * 256 + threadIdx.x;
    if (i >= ETOT) return;
    int src, dst;
    if (i < EIN) { src = ei[i]; dst = ei[EIN + i]; }
    else { src = i - EIN; dst = src; }
    int pos = atomicAdd(&cursor[dst], 1);
    col_src[pos] = src;
}

// ---------------- bf16 MFMA GEMM: C[M,N] = A[M,K] @ BT[N,K]^T ----------------
#define GBM 128
#define GBN 128
#define GBK 32
#define LPAD 8

__global__ __launch_bounds__(256) void gemm_bt_bf16(const __hip_bfloat16* __restrict__ A,
                                                    const __hip_bfloat16* __restrict__ BT,
                                                    float* __restrict__ C,
                                                    __hip_bfloat16* __restrict__ Cb,
                                                    int M, int N, int K) {
    __shared__ __align__(16) short As[GBM][GBK + LPAD];
    __shared__ __align__(16) short Bs[GBN][GBK + LPAD];
    int tid = threadIdx.x;
    int wid = tid >> 6, lane = tid & 63;
    int wr = wid >> 1, wc = wid & 1;
    int brow = blockIdx.y * GBM, bcol = blockIdx.x * GBN;

    ffrag acc[4][4] = {};

    int srow = tid >> 2;        // 0..63
    int skq  = (tid & 3) * 8;   // 0,8,16,24

    int kq = (lane >> 4) * 8;
    int ra = lane & 15;

    for (int k0 = 0; k0 < K; k0 += GBK) {
#pragma unroll
        for (int p = 0; p < 2; ++p) {
            int r = srow + p * 64;
            int gr = brow + r;
            bfrag va = {0,0,0,0,0,0,0,0};
            if (gr < M) va = *(const bfrag*)(A + (size_t)gr * K + k0 + skq);
            *(bfrag*)&As[r][skq] = va;
            int gc = bcol + r;
            bfrag vb = {0,0,0,0,0,0,0,0};
            if (gc < N) vb = *(const bfrag*)(BT + (size_t)gc * K + k0 + skq);
            *(bfrag*)&Bs[r][skq] = vb;
        }
        __syncthreads();
        bfrag af[4], bf[4];
#pragma unroll
        for (int m = 0; m < 4; ++m) af[m] = *(const bfrag*)&As[wr * 64 + m * 16 + ra][kq];
#pragma unroll
        for (int n = 0; n < 4; ++n) bf[n] = *(const bfrag*)&Bs[wc * 64 + n * 16 + ra][kq];
#pragma unroll
        for (int m = 0; m < 4; ++m)
#pragma unroll
            for (int n = 0; n < 4; ++n)
                acc[m][n] = __builtin_amdgcn_mfma_f32_16x16x32_bf16(af[m], bf[n], acc[m][n], 0, 0, 0);
        __syncthreads();
    }

    int cr = (lane >> 4) * 4;
    int cc = lane & 15;
#pragma unroll
    for (int m = 0; m < 4; ++m) {
#pragma unroll
        for (int n = 0; n < 4; ++n) {
#pragma unroll
            for (int r = 0; r < 4; ++r) {
                int grow = brow + wr * 64 + m * 16 + cr + r;
                int gcol = bcol + wc * 64 + n * 16 + cc;
                if (grow < M && gcol < N) {
                    float v = acc[m][n][r];
                    C[(size_t)grow * N + gcol] = v;
                    if (Cb) Cb[(size_t)grow * N + gcol] = __float2bfloat16(v);
                }
            }
        }
    }
}

// ---------------- per-(node,head) attention dots ----------------
__global__ void node_attn_kernel(const float* __restrict__ h, const float* __restrict__ asrc,
                                 const float* __restrict__ adst, float* __restrict__ a_s,
                                 float* __restrict__ a_d, int H, int total) {
    int id = blockIdx.x * 4 + (threadIdx.x >> 6);
    int lane = threadIdx.x & 63;
    if (id >= total) return;
    int node = id / H, head = id - node * H;
    float v = h[(size_t)node * H * 64 + head * 64 + lane];
    float ds = v * asrc[head * 64 + lane];
    float dd = v * adst[head * 64 + lane];
    for (int o = 32; o; o >>= 1) { ds += __shfl_xor(ds, o); dd += __shfl_xor(dd, o); }
    if (lane == 0) { a_s[id] = ds; a_d[id] = dd; }
}

// ---------------- GAT aggregate, 8 heads: bf16 gather, thread = 2 consecutive ch ----------------
__global__ __launch_bounds__(256) void gat_agg8(const __hip_bfloat16* __restrict__ h,  // [N,512] bf16
                                                const float* __restrict__ a_s,          // [N,8]
                                                const float* __restrict__ a_d,          // [N,8]
                                                const int* __restrict__ row_ptr,
                                                const int* __restrict__ col_src,
                                                const float* __restrict__ bias,         // [512]
                                                __hip_bfloat16* __restrict__ out)       // [N,512] bf16 (relu)
{
    int n = blockIdx.x;
    int tid = threadIdx.x;
    int hh = tid >> 5;            // head 0..7 (32 threads per head)
    int c0 = tid * 2;             // channels c0, c0+1, same head
    __shared__ float ad_sh[8];
    __shared__ float m_sh[8];
    if (tid < 8) ad_sh[tid] = a_d[n * 8 + tid];
    int r0 = row_ptr[n], r1 = row_ptr[n + 1];
    __syncthreads();
    float ad = ad_sh[hh];

    // pass 1: per-head max, one 32-lane group per head
    float lm = -1e30f;
    for (int k = r0 + (tid & 31); k < r1; k += 32) {
        float e = a_s[col_src[k] * 8 + hh] + ad;
        e = e > 0.f ? e : 0.2f * e;
        lm = fmaxf(lm, e);
    }
#pragma unroll
    for (int o = 16; o; o >>= 1) lm = fmaxf(lm, __shfl_xor(lm, o));
    if ((tid & 31) == 0) m_sh[hh] = lm;
    __syncthreads();
    float m = m_sh[hh];

    // pass 2: gather + weighted sum (one alpha per thread, 2 channels)
    float acc0 = 0.f, acc1 = 0.f, ssum = 0.f;
    const unsigned short* hu = (const unsigned short*)h;
    for (int k = r0; k < r1; ++k) {
        int s = col_src[k];
        float e = a_s[s * 8 + hh] + ad;
        e = e > 0.f ? e : 0.2f * e;
        float al = __expf(e - m);
        unsigned v = *(const unsigned*)(hu + (size_t)s * 512 + c0);
        acc0 += al * bf2f((unsigned short)(v & 0xffff));
        acc1 += al * bf2f((unsigned short)(v >> 16));
        ssum += al;
    }
    float inv = 1.f / (ssum + 1e-16f);
    float o0 = fmaxf(acc0 * inv + bias[c0], 0.f);
    float o1 = fmaxf(acc1 * inv + bias[c0 + 1], 0.f);
    unsigned pk = (unsigned)f2bf(o0) | ((unsigned)f2bf(o1) << 16);
    *(unsigned*)((unsigned short*)out + (size_t)n * 512 + c0) = pk;
}

// ---------------- GAT aggregate, 1 head x 64 ch (layer 2) ----------------
__global__ __launch_bounds__(256) void gat_agg1(const float* __restrict__ h,    // [N,64]
                                                const float* __restrict__ a_s,  // [N]
                                                const float* __restrict__ a_d,  // [N]
                                                const int* __restrict__ row_ptr,
                                                const int* __restrict__ col_src,
                                                const float* __restrict__ bias, // [64]
                                                float* __restrict__ out) {
    int n = blockIdx.x * 4 + (threadIdx.x >> 6);
    int lane = threadIdx.x & 63;
    if (n >= NN) return;
    int r0 = row_ptr[n], r1 = row_ptr[n + 1];
    float ad = a_d[n];
    float lm = -1e30f;
    for (int k = r0 + lane; k < r1; k += 64) {
        float e = a_s[col_src[k]] + ad;
        e = e > 0.f ? e : 0.2f * e;
        lm = fmaxf(lm, e);
    }
    for (int o = 32; o; o >>= 1) lm = fmaxf(lm, __shfl_xor(lm, o));
    float acc = 0.f, ssum = 0.f;
    for (int k = r0; k < r1; ++k) {
        int s = col_src[k];
        float e = a_s[s] + ad; e = e > 0.f ? e : 0.2f * e;
        float al = __expf(e - lm);
        acc += al * h[(size_t)s * 64 + lane];
        ssum += al;
    }
    out[(size_t)n * 64 + lane] = acc / (ssum + 1e-16f) + bias[lane];
}

// ---------------- fused pooling + classifier (batch is sorted) ----------------
__global__ __launch_bounds__(256) void pool_classify(const float* __restrict__ h,     // [N,64]
                                                     const int* __restrict__ batch,
                                                     const float* __restrict__ cW1, const float* __restrict__ cb1,
                                                     const float* __restrict__ cW2, const float* __restrict__ cb2,
                                                     float* __restrict__ out) {
    int g = blockIdx.x;
    int tid = threadIdx.x;
    int lane = tid & 63, w = tid >> 6;

    int lo = 0, hi = NN;
    while (lo < hi) { int mid = (lo + hi) >> 1; if (batch[mid] < g) lo = mid + 1; else hi = mid; }
    int s = lo;
    lo = s; hi = NN;
    while (lo < hi) { int mid = (lo + hi) >> 1; if (batch[mid] < g + 1) lo = mid + 1; else hi = mid; }
    int e = lo;

    float sum = 0.f, mx = -1e30f;
    for (int n = s + w; n < e; n += 4) {
        float v = h[(size_t)n * 64 + lane];
        sum += v; mx = fmaxf(mx, v);
    }
    __shared__ float ssum[4][64], smax[4][64];
    __shared__ float gv[128], c1[64];
    ssum[w][lane] = sum; smax[w][lane] = mx;
    __syncthreads();
    if (tid < 64) {
        float s4 = ssum[0][tid] + ssum[1][tid] + ssum[2][tid] + ssum[3][tid];
        float m4 = fmaxf(fmaxf(smax[0][tid], smax[1][tid]), fmaxf(smax[2][tid], smax[3][tid]));
        int cntv = e - s;
        float c = (float)(cntv > 1 ? cntv : 1);
        gv[tid] = s4 / c;
        gv[64 + tid] = m4;
    }
    __syncthreads();
    if (tid < 64) {
        float acc = cb1[tid];
        for (int k = 0; k < 128; k++) acc += gv[k] * cW1[k * 64 + tid];
        c1[tid] = fmaxf(acc, 0.f);
    }
    __syncthreads();
    if (tid < OUTD) {
        float o = cb2[tid];
        for (int k = 0; k < 64; k++) o += c1[k] * cW2[k * OUTD + tid];
        out[g * OUTD + tid] = o;
    }
}

// ---------------- launch ----------------
extern "C" void kernel_launch(void* const* d_in, const int* in_sizes, int n_in,
                              void* d_out, int out_size, void* d_ws, size_t ws_size,
                              hipStream_t stream) {
    const float* x     = (const float*)d_in[0];
    const int*   ei    = (const int*)d_in[1];
    const int*   batch = (const int*)d_in[2];
    const float* W0    = (const float*)d_in[3];
    const float* asrc0 = (const float*)d_in[4];
    const float* adst0 = (const float*)d_in[5];
    const float* b0    = (const float*)d_in[6];
    const float* W1    = (const float*)d_in[7];
    const float* asrc1 = (const float*)d_in[8];
    const float* adst1 = (const float*)d_in[9];
    const float* b1    = (const float*)d_in[10];
    const float* W2    = (const float*)d_in[11];
    const float* asrc2 = (const float*)d_in[12];
    const float* adst2 = (const float*)d_in[13];
    const float* b2    = (const float*)d_in[14];
    const float* cW1   = (const float*)d_in[15];
    const float* cb1   = (const float*)d_in[16];
    const float* cW2   = (const float*)d_in[17];
    const float* cb2   = (const float*)d_in[18];
    float* out = (float*)d_out;

    char* ws = (char*)d_ws;
    size_t off = 0;
    auto alloc = [&](size_t bytes) { void* p = ws + off; off += (bytes + 255) & ~(size_t)255; return p; };
    float* bufA  = (float*)alloc((size_t)NN * D0 * 4);
    __hip_bfloat16* bufAb = (__hip_bfloat16*)alloc((size_t)NN * D0 * 2);
    __hip_bfloat16* bufBb = (__hip_bfloat16*)alloc((size_t)NN * D0 * 2);
    float* bufC  = (float*)alloc((size_t)NN * 64 * 4);
    float* bufD  = (float*)alloc((size_t)NN * 64 * 4);
    __hip_bfloat16* xb   = (__hip_bfloat16*)alloc((size_t)NN * INDIM * 2);
    __hip_bfloat16* W0T  = (__hip_bfloat16*)alloc((size_t)D0 * INDIM * 2);
    __hip_bfloat16* W1T  = (__hip_bfloat16*)alloc((size_t)D0 * D0 * 2);
    __hip_bfloat16* W2T  = (__hip_bfloat16*)alloc((size_t)64 * D0 * 2);
    float* a_s     = (float*)alloc((size_t)NN * HEADS * 4);
    float* a_d     = (float*)alloc((size_t)NN * HEADS * 4);
    int*   cnt     = (int*)alloc((size_t)NN * 4);
    int*   row_ptr = (int*)alloc((size_t)(NN + 1) * 4);
    int*   cursor  = (int*)alloc((size_t)NN * 4);
    int*   col_src = (int*)alloc((size_t)ETOT * 4);
    (void)ws_size; (void)n_in; (void)in_sizes; (void)out_size;

    cast_bf16_kernel<<<(NN * INDIM + 255) / 256, 256, 0, stream>>>(x, xb, NN * INDIM);
    transpose_cast_kernel<<<dim3(D0 / 32, INDIM / 32), 256, 0, stream>>>(W0, W0T, INDIM, D0);
    transpose_cast_kernel<<<dim3(D0 / 32, D0 / 32), 256, 0, stream>>>(W1, W1T, D0, D0);
    transpose_cast_kernel<<<dim3(64 / 32, D0 / 32), 256, 0, stream>>>(W2, W2T, D0, 64);

    hipMemsetAsync(cnt, 0, (size_t)NN * 4, stream);
    count_kernel<<<(ETOT + 255) / 256, 256, 0, stream>>>(ei, cnt);
    scan_kernel<<<1, 1024, 0, stream>>>(cnt, row_ptr, cursor);
    scatter_kernel<<<(ETOT + 255) / 256, 256, 0, stream>>>(ei, cursor, col_src);

    dim3 gg8(D0 / GBN, (NN + GBM - 1) / GBM);   // (4, 79)
    dim3 gg1(1, (NN + GBM - 1) / GBM);          // (1, 79)

    // ---- layer 0 ----
    gemm_bt_bf16<<<gg8, 256, 0, stream>>>(xb, W0T, bufA, bufAb, NN, D0, INDIM);
    node_attn_kernel<<<(NN * HEADS + 3) / 4, 256, 0, stream>>>(bufA, asrc0, adst0, a_s, a_d, HEADS, NN * HEADS);
    gat_agg8<<<NN, 256, 0, stream>>>(bufAb, a_s, a_d, row_ptr, col_src, b0, bufBb);

    // ---- layer 1 ----
    gemm_bt_bf16<<<gg8, 256, 0, stream>>>(bufBb, W1T, bufA, bufAb, NN, D0, D0);
    node_attn_kernel<<<(NN * HEADS + 3) / 4, 256, 0, stream>>>(bufA, asrc1, adst1, a_s, a_d, HEADS, NN * HEADS);
    gat_agg8<<<NN, 256, 0, stream>>>(bufAb, a_s, a_d, row_ptr, col_src, b1, bufBb);

    // ---- layer 2 (1 head) ----
    gemm_bt_bf16<<<gg1, 256, 0, stream>>>(bufBb, W2T, bufC, (__hip_bfloat16*)nullptr, NN, 64, D0);
    node_attn_kernel<<<(NN + 3) / 4, 256, 0, stream>>>(bufC, asrc2, adst2, a_s, a_d, 1, NN);
    gat_agg1<<<(NN + 3) / 4, 256, 0, stream>>>(bufC, a_s, a_d, row_ptr, col_src, b2, bufD);

    // ---- fused pooling + classifier ----
    pool_classify<<<NG, 256, 0, stream>>>(bufD, batch, cW1, cb1, cW2, cb2, out);
}